// Round 6
// baseline (213.721 us; speedup 1.0000x reference)
//
#include <hip/hip_runtime.h>
#include <hip/hip_bf16.h>
#include <stdint.h>

#define B_  4
#define S_  2048
#define D_  1024
#define H_  1024
#define BS_ (B_*S_)    // 8192
#define N3H (3*H_)     // 3072

typedef __bf16 bf16x8 __attribute__((ext_vector_type(8)));
typedef float  f32x4  __attribute__((ext_vector_type(4)));
typedef unsigned short u16x8 __attribute__((ext_vector_type(8)));

__device__ __forceinline__ unsigned short f2bf(float x) {
    unsigned u = __float_as_uint(x);
    return (unsigned short)((u + 0x7FFFu + ((u >> 16) & 1u)) >> 16);  // RNE
}
__device__ __forceinline__ float bf2f(unsigned short h) {
    return __uint_as_float(((unsigned)h) << 16);
}

__device__ __forceinline__ void gload_lds16(const void* g, void* l) {
    __builtin_amdgcn_global_load_lds(
        (const __attribute__((address_space(1))) void*)g,
        (__attribute__((address_space(3))) void*)l, 16, 0, 0);
}

#define BAR __builtin_amdgcn_s_barrier()
#define DS_FENCE do { asm volatile("s_waitcnt lgkmcnt(0)" ::: "memory"); \
                      __builtin_amdgcn_sched_barrier(0); } while (0)

// ---------------------------------------------------------------------------
// gemm3b: 128x128-tile bt-GEMM, BK=32, 256 threads (2x2 waves, wave 64x64,
// acc 4x4), triple-buffered 48 KiB LDS (3 bufs x 16 KiB: A 8K | B 8K) ->
// 3 blocks/CU, 12 waves/CU (m97 occupancy regime: inter-block TLP fills the
// barrier/vmcnt stalls that pinned the 1-block/CU configs at 30% MfmaUtil).
// st_16x32 swizzle, conflict-free (verified rounds 2-5).
// Per K-tile t (read buf t%3, stage buf (t+2)%3 -- disjoint from both live
// read bufs; phase t-1's lgkm(0) drained all reads of that buf before its
// ending barrier, so post-barrier stage writes are race-free):
//   rd A m0-3 (4) + B n0-3 (4); STAGE A(2)+B(2) of tile t+2;
//   BAR; lgkm(0); 16 MFMA; vmcnt(4) [drain t+1's 4, keep t+2's 4]; BAR
// Grid: 1D, XCD-chunked + 2D sub-chunk ((grid/8) % (4*NXt) == 0 required).
// ---------------------------------------------------------------------------
template<int EPI>
__global__ __launch_bounds__(256, 3) void gemm3b(
    const unsigned short* __restrict__ A,
    const unsigned short* __restrict__ Bm,
    int NXt, int NYt, int N, int K,
    long long sAz, long long sBz, long long sOz,
    void* __restrict__ out0, void* __restrict__ out1, void* __restrict__ out2,
    const float* __restrict__ bias, float scale)
{
    __shared__ __align__(16) char lds[3 * 16384];

    // XCD chunking + within-chunk 2D sub-order
    const int nt_g = (int)gridDim.x;
    const int bid = (int)blockIdx.x;
    const int C = nt_g >> 3;
    const int c = bid >> 3;
    const int xcd = bid & 7;
    const int qq = c >> 2;
    const int txl = qq % NXt;
    const int rest = (c & 3) + 4 * (qq / NXt);
    const int tile = xcd * C + rest * NXt + txl;
    const int tx = tile % NXt;
    const int rest2 = tile / NXt;
    const int ty = rest2 % NYt;
    const int tz = rest2 / NYt;

    const unsigned short* Ab = A  + (long long)tz * sAz;
    const unsigned short* Bb = Bm + (long long)tz * sBz;
    const int rowBase = ty * 128;
    const int colBase = tx * 128;
    const int tid = threadIdx.x;
    const int w = tid >> 6, l = tid & 63;
    const int wr = w >> 1, wc = w & 1;          // 2M x 2N waves
    const int fr = l & 15, fq = l >> 4;

    // staging source decode (inverse st_16x32 swizzle); per matrix 8 KiB =
    // 8 subtiles of 1 KiB; thread covers linear bytes o = j*4096 + tid*16
    int sr[2], scl[2];
#pragma unroll
    for (int j = 0; j < 2; j++) {
        int o  = j * 4096 + tid * 16;
        int st = o >> 10;                       // 0..7 (16-row group)
        int wi = o & 1023;
        wi ^= ((wi >> 9) & 1) << 5;             // involution
        sr[j]  = st * 16 + (wi >> 6);           // row 0..127
        scl[j] = (wi & 63) >> 1;                // k 0..31
    }

    auto STAGE_A = [&](char* buf, int t) {
        const unsigned short* base = Ab + (long long)rowBase * K + t * 32;
#pragma unroll
        for (int j = 0; j < 2; j++)
            gload_lds16(base + (long long)sr[j] * K + scl[j],
                        buf + j * 4096 + w * 1024);
    };
    auto STAGE_B = [&](char* buf, int t) {
        const unsigned short* base = Bb + (long long)colBase * K + t * 32;
#pragma unroll
        for (int j = 0; j < 2; j++)
            gload_lds16(base + (long long)sr[j] * K + scl[j],
                        buf + 8192 + j * 4096 + w * 1024);
    };

    const int abase = (fr * 64 + fq * 16) ^ ((fr & 8) << 2);

    f32x4 acc[4][4];
#pragma unroll
    for (int m = 0; m < 4; m++)
#pragma unroll
        for (int n = 0; n < 4; n++) acc[m][n] = (f32x4){0.f, 0.f, 0.f, 0.f};

    const int NT = K >> 5;

    // prologue: tiles 0 (buf0) and 1 (buf1); drain tile0's 4 loads
    STAGE_A(lds, 0); STAGE_B(lds, 0);
    STAGE_A(lds + 16384, 1); STAGE_B(lds + 16384, 1);
    asm volatile("s_waitcnt vmcnt(4)" ::: "memory");
    BAR;
    __builtin_amdgcn_sched_barrier(0);

    bf16x8 af[4], bf[4];

    for (int t = 0; t < NT; ++t) {
        const char* bc = lds + (t % 3) * 16384;
        char* bs = lds + ((t + 2) % 3) * 16384;
        int ts = t + 2; if (ts >= NT) ts -= NT;

#pragma unroll
        for (int m = 0; m < 4; m++)
            af[m] = *(const bf16x8*)(bc + (wr * 4 + m) * 1024 + abase);
#pragma unroll
        for (int n = 0; n < 4; n++)
            bf[n] = *(const bf16x8*)(bc + 8192 + (wc * 4 + n) * 1024 + abase);
        STAGE_A(bs, ts); STAGE_B(bs, ts);
        BAR; DS_FENCE;
        __builtin_amdgcn_s_setprio(1);
#pragma unroll
        for (int m = 0; m < 4; m++)
#pragma unroll
            for (int n = 0; n < 4; n++)
                acc[m][n] = __builtin_amdgcn_mfma_f32_16x16x32_bf16(
                    af[m], bf[n], acc[m][n], 0, 0, 0);
        __builtin_amdgcn_s_setprio(0);
        asm volatile("s_waitcnt vmcnt(4)" ::: "memory");
        BAR;
        __builtin_amdgcn_sched_barrier(0);
    }

    asm volatile("s_waitcnt vmcnt(0) lgkmcnt(0)" ::: "memory");

    // epilogue: row = rowBase + wr*64 + m*16 + fq*4 + j; col = colBase + wc*64 + n*16 + fr
    const int crow0 = rowBase + wr * 64 + fq * 4;
    const int ccol0 = colBase + wc * 64 + fr;

#pragma unroll
    for (int n = 0; n < 4; n++) {
        const int col = ccol0 + n * 16;
        if constexpr (EPI == 0) {
            const float bv = bias[col];
            const int seg = col >> 10, scn = col & 1023;
            unsigned short* dst =
                (unsigned short*)(seg == 0 ? out0 : (seg == 1 ? out1 : out2));
#pragma unroll
            for (int m = 0; m < 4; m++) {
                const int r0 = crow0 + m * 16;
#pragma unroll
                for (int j = 0; j < 4; j++)
                    dst[(long long)(r0 + j) * 1024 + scn] = f2bf(acc[m][n][j] + bv);
            }
        } else if constexpr (EPI == 1) {
            unsigned short* dst = (unsigned short*)out0 + (long long)tz * sOz;
#pragma unroll
            for (int m = 0; m < 4; m++) {
                const int r0 = crow0 + m * 16;
#pragma unroll
                for (int j = 0; j < 4; j++)
                    dst[(long long)(r0 + j) * N + col] = f2bf(acc[m][n][j] * scale);
            }
        } else {
            float* dst = (float*)out0;
            const float bv = bias[col];
#pragma unroll
            for (int m = 0; m < 4; m++) {
                const int r0 = crow0 + m * 16;
#pragma unroll
                for (int j = 0; j < 4; j++)
                    dst[(long long)(r0 + j) * N + col] = acc[m][n][j] + bv;
            }
        }
    }
}

// ---------------------------------------------------------------------------
// gemm256: verified 256x256 8-phase kernel — kept for scores (256 blocks = 1.0/CU)
// ---------------------------------------------------------------------------
template<int EPI>
__global__ __launch_bounds__(512, 2) void gemm256(
    const unsigned short* __restrict__ A,
    const unsigned short* __restrict__ Bm,
    int M, int N, int K,
    long long sAz, long long sBz, long long sOz,
    void* __restrict__ out0, void* __restrict__ out1, void* __restrict__ out2,
    const float* __restrict__ bias, float scale)
{
    __shared__ __align__(16) char lds[131072];
    (void)M;

    const unsigned short* Ab = A  + blockIdx.z * sAz;
    const unsigned short* Bb = Bm + blockIdx.z * sBz;
    const int rowBase = blockIdx.y * 256;
    const int colBase = blockIdx.x * 256;
    const int tid = threadIdx.x;
    const int w = tid >> 6, l = tid & 63;
    const int wr = w >> 2, wc = w & 3;
    const int fr = l & 15, fq = l >> 4;

    int sr[2], scl[2];
#pragma unroll
    for (int j = 0; j < 2; j++) {
        int o  = j * 8192 + tid * 16;
        int st = o >> 10;
        int wi = o & 1023;
        wi ^= ((wi >> 9) & 1) << 5;
        sr[j]  = (st >> 1) * 16 + (wi >> 6);
        scl[j] = (st & 1) * 32 + ((wi & 63) >> 1);
    }

    auto STAGE = [&](int buf, int which, int tile) {
        const unsigned short* mat = (which < 2) ? Ab : Bb;
        const int rt0 = ((which < 2) ? rowBase : colBase) + (which & 1) * 128;
        char* dst = lds + buf * 65536 + (which >> 1) * 32768
                        + (which & 1) * 16384 + w * 1024;
        const int k0 = tile * 64;
#pragma unroll
        for (int j = 0; j < 2; j++) {
            const unsigned short* src =
                mat + (long long)(rt0 + sr[j]) * K + k0 + scl[j];
            gload_lds16(src, dst + j * 8192);
        }
    };

    const int abase = (fr * 64 + fq * 16) ^ ((fr & 8) << 2);
    const char* Ah[2] = { lds + wr * 16384, lds + 65536 + wr * 16384 };
    const char* Bh[2] = { lds + 32768 + (wc >> 1) * 16384,
                          lds + 98304 + (wc >> 1) * 16384 };
    const int bn0 = (wc & 1) * 8192;

#define LA(b, m, kk) (*(const bf16x8*)(Ah[b] + (m)*2048 + (kk)*1024 + abase))
#define LB(b, n, kk) (*(const bf16x8*)(Bh[b] + bn0 + (n)*2048 + (kk)*1024 + abase))
#define MFMA16(AF, BF, MOFF, NOFF) do { \
    __builtin_amdgcn_s_setprio(1); \
    _Pragma("unroll") for (int m_ = 0; m_ < 4; m_++) \
    _Pragma("unroll") for (int n_ = 0; n_ < 2; n_++) \
    _Pragma("unroll") for (int k_ = 0; k_ < 2; k_++) \
        acc[(MOFF)+m_][(NOFF)+n_] = __builtin_amdgcn_mfma_f32_16x16x32_bf16( \
            AF[m_][k_], BF[n_][k_], acc[(MOFF)+m_][(NOFF)+n_], 0, 0, 0); \
    __builtin_amdgcn_s_setprio(0); } while (0)

    f32x4 acc[8][4];
#pragma unroll
    for (int m = 0; m < 8; m++)
#pragma unroll
        for (int n = 0; n < 4; n++) acc[m][n] = (f32x4){0.f, 0.f, 0.f, 0.f};

    const int NT = K >> 6;

    STAGE(0, 0, 0); STAGE(0, 1, 0); STAGE(0, 2, 0); STAGE(0, 3, 0);
    STAGE(1, 0, 1); STAGE(1, 1, 1);
    asm volatile("s_waitcnt vmcnt(4)" ::: "memory");
    BAR;
    __builtin_amdgcn_sched_barrier(0);

    bf16x8 afA[4][2], afB[4][2], bfA[2][2], bfB[2][2];

    for (int i = 0; i < NT / 2; i++) {
        const int t1 = 2 * i + 1;
        int t2 = 2 * i + 2; if (t2 >= NT) t2 -= NT;
        int t3 = 2 * i + 3; if (t3 >= NT) t3 -= NT;

#pragma unroll
        for (int m = 0; m < 4; m++) { afA[m][0] = LA(0, m, 0); afA[m][1] = LA(0, m, 1); }
#pragma unroll
        for (int n = 0; n < 2; n++) { bfA[n][0] = LB(0, n, 0); bfA[n][1] = LB(0, n, 1); }
        STAGE(1, 2, t1);
        BAR; DS_FENCE;
        MFMA16(afA, bfA, 0, 0);
        BAR;
#pragma unroll
        for (int m = 0; m < 4; m++) { afB[m][0] = LA(0, 4 + m, 0); afB[m][1] = LA(0, 4 + m, 1); }
        STAGE(1, 3, t1);
        BAR; DS_FENCE;
        MFMA16(afB, bfA, 4, 0);
        BAR;
#pragma unroll
        for (int n = 0; n < 2; n++) { bfB[n][0] = LB(0, 2 + n, 0); bfB[n][1] = LB(0, 2 + n, 1); }
        STAGE(0, 0, t2);
        BAR; DS_FENCE;
        MFMA16(afA, bfB, 0, 2);
        BAR;
        STAGE(0, 1, t2);
        BAR;
        MFMA16(afB, bfB, 4, 2);
        asm volatile("s_waitcnt vmcnt(4)" ::: "memory");
        BAR;
        __builtin_amdgcn_sched_barrier(0);

#pragma unroll
        for (int m = 0; m < 4; m++) { afA[m][0] = LA(1, m, 0); afA[m][1] = LA(1, m, 1); }
#pragma unroll
        for (int n = 0; n < 2; n++) { bfA[n][0] = LB(1, n, 0); bfA[n][1] = LB(1, n, 1); }
        STAGE(0, 2, t2);
        BAR; DS_FENCE;
        MFMA16(afA, bfA, 0, 0);
        BAR;
#pragma unroll
        for (int m = 0; m < 4; m++) { afB[m][0] = LA(1, 4 + m, 0); afB[m][1] = LA(1, 4 + m, 1); }
        STAGE(0, 3, t2);
        BAR; DS_FENCE;
        MFMA16(afB, bfA, 4, 0);
        BAR;
#pragma unroll
        for (int n = 0; n < 2; n++) { bfB[n][0] = LB(1, 2 + n, 0); bfB[n][1] = LB(1, 2 + n, 1); }
        STAGE(1, 0, t3);
        BAR; DS_FENCE;
        MFMA16(afA, bfB, 0, 2);
        BAR;
        STAGE(1, 1, t3);
        BAR;
        MFMA16(afB, bfB, 4, 2);
        asm volatile("s_waitcnt vmcnt(4)" ::: "memory");
        BAR;
        __builtin_amdgcn_sched_barrier(0);
    }

    asm volatile("s_waitcnt vmcnt(0) lgkmcnt(0)" ::: "memory");

    const int crow0 = rowBase + wr * 128 + fq * 4;
    const int ccol0 = colBase + wc * 64 + fr;

#pragma unroll
    for (int n = 0; n < 4; n++) {
        const int col = ccol0 + n * 16;
        if constexpr (EPI == 1) {
            unsigned short* dst = (unsigned short*)out0 + blockIdx.z * sOz;
#pragma unroll
            for (int m = 0; m < 8; m++) {
                const int r0 = crow0 + m * 16;
#pragma unroll
                for (int j = 0; j < 4; j++)
                    dst[(long long)(r0 + j) * N + col] = f2bf(acc[m][n][j] * scale);
            }
        }
    }
    (void)out1; (void)out2; (void)bias;
#undef LA
#undef LB
#undef MFMA16
}

// f32 -> bf16 elementwise (8/thread, vectorized)
__global__ __launch_bounds__(256) void conv_f32_bf16(
    const float* __restrict__ in, unsigned short* __restrict__ out, int n8)
{
    for (int i = blockIdx.x * blockDim.x + threadIdx.x; i < n8;
         i += gridDim.x * blockDim.x) {
        const float4 a = ((const float4*)in)[2 * i];
        const float4 b = ((const float4*)in)[2 * i + 1];
        u16x8 o;
        o[0] = f2bf(a.x); o[1] = f2bf(a.y); o[2] = f2bf(a.z); o[3] = f2bf(a.w);
        o[4] = f2bf(b.x); o[5] = f2bf(b.y); o[6] = f2bf(b.z); o[7] = f2bf(b.w);
        ((u16x8*)out)[i] = o;
    }
}

// out[cols][rows] (bf16) = transpose(in[rows][cols] f32)
__global__ __launch_bounds__(256) void tconv_f32_bf16(
    const float* __restrict__ in, unsigned short* __restrict__ out,
    int rows, int cols)
{
    __shared__ float t[32][33];
    const int c0 = blockIdx.x * 32, r0 = blockIdx.y * 32;
    const int tx = threadIdx.x & 31, ty = threadIdx.x >> 5;
#pragma unroll
    for (int i = 0; i < 4; i++)
        t[ty + 8 * i][tx] = in[(long long)(r0 + ty + 8 * i) * cols + c0 + tx];
    __syncthreads();
#pragma unroll
    for (int i = 0; i < 4; i++)
        out[(long long)(c0 + ty + 8 * i) * rows + r0 + tx] = f2bf(t[tx][ty + 8 * i]);
}

// bf16 transpose, batched via grid.z
__global__ __launch_bounds__(256) void t_bf16(
    const unsigned short* __restrict__ in, unsigned short* __restrict__ out,
    int rows, int cols, long long sIz, long long sOz)
{
    __shared__ unsigned short t[32][33];
    in  += blockIdx.z * sIz;
    out += blockIdx.z * sOz;
    const int c0 = blockIdx.x * 32, r0 = blockIdx.y * 32;
    const int tx = threadIdx.x & 31, ty = threadIdx.x >> 5;
#pragma unroll
    for (int i = 0; i < 4; i++)
        t[ty + 8 * i][tx] = in[(long long)(r0 + ty + 8 * i) * cols + c0 + tx];
    __syncthreads();
#pragma unroll
    for (int i = 0; i < 4; i++)
        out[(long long)(c0 + ty + 8 * i) * rows + r0 + tx] = t[tx][ty + 8 * i];
}

// in-place row softmax over S_=2048 bf16 logits; one block (256 thr) per row
__global__ __launch_bounds__(256) void softmax_rows(unsigned short* __restrict__ sc)
{
    const long long row = blockIdx.x;
    unsigned short* p = sc + row * S_;
    const int tid = threadIdx.x, w = tid >> 6, l = tid & 63;

    u16x8 v = *reinterpret_cast<const u16x8*>(&p[tid * 8]);
    float f[8];
#pragma unroll
    for (int i = 0; i < 8; i++) f[i] = bf2f(v[i]);

    float m = f[0];
#pragma unroll
    for (int i = 1; i < 8; i++) m = fmaxf(m, f[i]);
    for (int o = 32; o; o >>= 1) m = fmaxf(m, __shfl_xor(m, o));
    __shared__ float red[8];
    if (l == 0) red[w] = m;
    __syncthreads();
    m = fmaxf(fmaxf(red[0], red[1]), fmaxf(red[2], red[3]));

    float s = 0.f;
#pragma unroll
    for (int i = 0; i < 8; i++) { f[i] = __expf(f[i] - m); s += f[i]; }
    for (int o = 32; o; o >>= 1) s += __shfl_xor(s, o);
    if (l == 0) red[4 + w] = s;
    __syncthreads();
    s = red[4] + red[5] + red[6] + red[7];

    const float inv = 1.0f / s;
    u16x8 o8;
#pragma unroll
    for (int i = 0; i < 8; i++) o8[i] = f2bf(f[i] * inv);
    *reinterpret_cast<u16x8*>(&p[tid * 8]) = o8;
}

extern "C" void kernel_launch(void* const* d_in, const int* in_sizes, int n_in,
                              void* d_out, int out_size, void* d_ws, size_t ws_size,
                              hipStream_t stream)
{
    (void)in_sizes; (void)n_in; (void)out_size; (void)ws_size;
    const float* x  = (const float*)d_in[0];
    const float* W1 = (const float*)d_in[1];
    const float* b1 = (const float*)d_in[2];
    const float* W2 = (const float*)d_in[3];
    const float* b2 = (const float*)d_in[4];
    float* out = (float*)d_out;

    char* ws = (char*)d_ws;
    size_t off = 0;
    auto alloc = [&](size_t bytes) {
        void* p = ws + off;
        off += (bytes + 255) & ~(size_t)255;
        return p;
    };
    unsigned short* xbf = (unsigned short*)alloc((size_t)BS_ * D_ * 2);
    unsigned short* w1t = (unsigned short*)alloc((size_t)N3H * D_ * 2);
    unsigned short* w2t = (unsigned short*)alloc((size_t)H_ * H_ * 2);
    unsigned short* q   = (unsigned short*)alloc((size_t)BS_ * H_ * 2);
    unsigned short* k   = (unsigned short*)alloc((size_t)BS_ * H_ * 2);
    unsigned short* v   = (unsigned short*)alloc((size_t)BS_ * H_ * 2);
    unsigned short* vt  = (unsigned short*)alloc((size_t)BS_ * H_ * 2);
    unsigned short* sc  = (unsigned short*)alloc((size_t)B_ * S_ * S_ * 2);
    unsigned short* ctx = v;  // alias: v is dead after transpose, before PV writes

    const float scale = 0.022097086912079608f;  // (2*D)^-0.5 = 1/sqrt(2048)

    conv_f32_bf16<<<dim3(2048), dim3(256), 0, stream>>>(x, xbf, BS_ * D_ / 8);
    tconv_f32_bf16<<<dim3(N3H / 32, D_ / 32), dim3(256), 0, stream>>>(W1, w1t, D_, N3H);
    tconv_f32_bf16<<<dim3(H_ / 32, H_ / 32), dim3(256), 0, stream>>>(W2, w2t, H_, H_);

    // QKV: [8192,3072] = xbf @ w1t^T, split q/k/v, +b1.
    // 24x64 = 1536 tiles of 128x128 = 2 rounds at 3 blocks/CU
    gemm3b<0><<<dim3(1536), dim3(256), 0, stream>>>(
        xbf, w1t, 24, 64, N3H, D_, 0LL, 0LL, 0LL, q, k, v, b1, 1.0f);

    // vt[b][h][s] = v[b][s][h]
    t_bf16<<<dim3(H_ / 32, S_ / 32, B_), dim3(256), 0, stream>>>(
        v, vt, S_, H_, (long long)S_ * H_, (long long)S_ * H_);

    // scores[b] = (q[b] @ k[b]^T) * scale  [2048,2048] bf16 — 256 blocks = 1.0/CU
    gemm256<1><<<dim3(S_ / 256, S_ / 256, B_), dim3(512), 0, stream>>>(
        q, k, S_, S_, H_, (long long)S_ * H_, (long long)S_ * H_, (long long)S_ * S_,
        sc, nullptr, nullptr, nullptr, scale);

    softmax_rows<<<dim3(BS_), dim3(256), 0, stream>>>(sc);

    // ctx[b] = P[b] @ vt[b]^T  [2048,1024] bf16.  8x16x4 = 512 tiles, K=2048
    gemm3b<1><<<dim3(512), dim3(256), 0, stream>>>(
        sc, vt, 8, 16, H_, S_, (long long)S_ * S_, (long long)H_ * S_,
        (long long)S_ * H_, ctx, nullptr, nullptr, nullptr, 1.0f);

    // out = ctx @ w2t^T + b2  [8192,1024] f32.  8x64 = 512 tiles
    gemm3b<3><<<dim3(512), dim3(256), 0, stream>>>(
        ctx, w2t, 8, 64, H_, H_, 0LL, 0LL, 0LL, out, nullptr, nullptr, b2, 1.0f);
}

// Round 7
// 195.597 us; speedup vs baseline: 1.0927x; 1.0927x over previous
//
#include <hip/hip_runtime.h>
#include <hip/hip_bf16.h>
#include <stdint.h>

#define B_  4
#define S_  2048
#define D_  1024
#define H_  1024
#define BS_ (B_*S_)    // 8192
#define N3H (3*H_)     // 3072

typedef __bf16 bf16x8 __attribute__((ext_vector_type(8)));
typedef float  f32x4  __attribute__((ext_vector_type(4)));
typedef unsigned short u16x8 __attribute__((ext_vector_type(8)));

__device__ __forceinline__ unsigned short f2bf(float x) {
    unsigned u = __float_as_uint(x);
    return (unsigned short)((u + 0x7FFFu + ((u >> 16) & 1u)) >> 16);  // RNE
}
__device__ __forceinline__ float bf2f(unsigned short h) {
    return __uint_as_float(((unsigned)h) << 16);
}

__device__ __forceinline__ void gload_lds16(const void* g, void* l) {
    __builtin_amdgcn_global_load_lds(
        (const __attribute__((address_space(1))) void*)g,
        (__attribute__((address_space(3))) void*)l, 16, 0, 0);
}

#define BAR __builtin_amdgcn_s_barrier()
#define DS_FENCE do { asm volatile("s_waitcnt lgkmcnt(0)" ::: "memory"); \
                      __builtin_amdgcn_sched_barrier(0); } while (0)

// ---------------------------------------------------------------------------
// gemm3b: 128x128-tile bt-GEMM, BK=32, 256 threads (2x2 waves, wave 64x64,
// acc 4x4), triple-buffered 48 KiB LDS, 3 blocks/CU. st_16x32 swizzle.
// Core loop unchanged from round 6 (verified).
// EPI 0: QKV split: q,k normal (+bias); v-segment blocks write vt TRANSPOSED
//        via LDS staging (eliminates the separate t_bf16 pass).
// EPI 3: f32 out, +bias (final projection)
// EPI 4: PV: bf16 out, rows scaled by 1/l[row] (l passed via `bias` pointer)
// ---------------------------------------------------------------------------
template<int EPI>
__global__ __launch_bounds__(256, 3) void gemm3b(
    const unsigned short* __restrict__ A,
    const unsigned short* __restrict__ Bm,
    int NXt, int NYt, int N, int K,
    long long sAz, long long sBz, long long sOz,
    void* __restrict__ out0, void* __restrict__ out1, void* __restrict__ out2,
    const float* __restrict__ bias, float scale)
{
    __shared__ __align__(16) char lds[3 * 16384];

    // XCD chunking + within-chunk 2D sub-order
    const int nt_g = (int)gridDim.x;
    const int bid = (int)blockIdx.x;
    const int C = nt_g >> 3;
    const int c = bid >> 3;
    const int xcd = bid & 7;
    const int qq = c >> 2;
    const int txl = qq % NXt;
    const int rest = (c & 3) + 4 * (qq / NXt);
    const int tile = xcd * C + rest * NXt + txl;
    const int tx = tile % NXt;
    const int rest2 = tile / NXt;
    const int ty = rest2 % NYt;
    const int tz = rest2 / NYt;

    const unsigned short* Ab = A  + (long long)tz * sAz;
    const unsigned short* Bb = Bm + (long long)tz * sBz;
    const int rowBase = ty * 128;
    const int colBase = tx * 128;
    const int tid = threadIdx.x;
    const int w = tid >> 6, l = tid & 63;
    const int wr = w >> 1, wc = w & 1;          // 2M x 2N waves
    const int fr = l & 15, fq = l >> 4;

    // staging source decode (inverse st_16x32 swizzle)
    int sr[2], scl[2];
#pragma unroll
    for (int j = 0; j < 2; j++) {
        int o  = j * 4096 + tid * 16;
        int st = o >> 10;
        int wi = o & 1023;
        wi ^= ((wi >> 9) & 1) << 5;
        sr[j]  = st * 16 + (wi >> 6);
        scl[j] = (wi & 63) >> 1;
    }

    auto STAGE_A = [&](char* buf, int t) {
        const unsigned short* base = Ab + (long long)rowBase * K + t * 32;
#pragma unroll
        for (int j = 0; j < 2; j++)
            gload_lds16(base + (long long)sr[j] * K + scl[j],
                        buf + j * 4096 + w * 1024);
    };
    auto STAGE_B = [&](char* buf, int t) {
        const unsigned short* base = Bb + (long long)colBase * K + t * 32;
#pragma unroll
        for (int j = 0; j < 2; j++)
            gload_lds16(base + (long long)sr[j] * K + scl[j],
                        buf + 8192 + j * 4096 + w * 1024);
    };

    const int abase = (fr * 64 + fq * 16) ^ ((fr & 8) << 2);

    f32x4 acc[4][4];
#pragma unroll
    for (int m = 0; m < 4; m++)
#pragma unroll
        for (int n = 0; n < 4; n++) acc[m][n] = (f32x4){0.f, 0.f, 0.f, 0.f};

    const int NT = K >> 5;

    STAGE_A(lds, 0); STAGE_B(lds, 0);
    STAGE_A(lds + 16384, 1); STAGE_B(lds + 16384, 1);
    asm volatile("s_waitcnt vmcnt(4)" ::: "memory");
    BAR;
    __builtin_amdgcn_sched_barrier(0);

    bf16x8 af[4], bf[4];

    for (int t = 0; t < NT; ++t) {
        const char* bc = lds + (t % 3) * 16384;
        char* bs = lds + ((t + 2) % 3) * 16384;
        int ts = t + 2; if (ts >= NT) ts -= NT;

#pragma unroll
        for (int m = 0; m < 4; m++)
            af[m] = *(const bf16x8*)(bc + (wr * 4 + m) * 1024 + abase);
#pragma unroll
        for (int n = 0; n < 4; n++)
            bf[n] = *(const bf16x8*)(bc + 8192 + (wc * 4 + n) * 1024 + abase);
        STAGE_A(bs, ts); STAGE_B(bs, ts);
        BAR; DS_FENCE;
        __builtin_amdgcn_s_setprio(1);
#pragma unroll
        for (int m = 0; m < 4; m++)
#pragma unroll
            for (int n = 0; n < 4; n++)
                acc[m][n] = __builtin_amdgcn_mfma_f32_16x16x32_bf16(
                    af[m], bf[n], acc[m][n], 0, 0, 0);
        __builtin_amdgcn_s_setprio(0);
        asm volatile("s_waitcnt vmcnt(4)" ::: "memory");
        BAR;
        __builtin_amdgcn_sched_barrier(0);
    }

    asm volatile("s_waitcnt vmcnt(0) lgkmcnt(0)" ::: "memory");
    BAR;   // all waves' in-flight DMA landed -> LDS reusable below

    const int crow0 = rowBase + wr * 64 + fq * 4;
    const int ccol0 = colBase + wc * 64 + fr;

    if constexpr (EPI == 0) {
        const int seg = colBase >> 10;           // block is column-aligned
        if (seg < 2) {
            unsigned short* dst = (unsigned short*)(seg == 0 ? out0 : out1);
#pragma unroll
            for (int n = 0; n < 4; n++) {
                const int col = ccol0 + n * 16;
                const float bv = bias[col];
                const int scn = col & 1023;
#pragma unroll
                for (int m = 0; m < 4; m++) {
                    const int r0 = crow0 + m * 16;
#pragma unroll
                    for (int j = 0; j < 4; j++)
                        dst[(long long)(r0 + j) * 1024 + scn] = f2bf(acc[m][n][j] + bv);
                }
            }
        } else {
            // v segment: stage into LDS [128][129], write transposed -> vt[b][h][s]
            unsigned short (*T)[129] = (unsigned short(*)[129])lds;
            const int lr0 = wr * 64 + fq * 4;
            const int lc0 = wc * 64 + fr;
#pragma unroll
            for (int n = 0; n < 4; n++) {
                const int lc = lc0 + n * 16;
                const float bv = bias[colBase + lc];
#pragma unroll
                for (int m = 0; m < 4; m++)
#pragma unroll
                    for (int j = 0; j < 4; j++)
                        T[lr0 + m * 16 + j][lc] = f2bf(acc[m][n][j] + bv);
            }
            BAR;
            const int s_loc = tid & 127, hh = tid >> 7;
            const int b = rowBase >> 11;
            const int s_glob = (rowBase & 2047) + s_loc;
            unsigned short* vt =
                (unsigned short*)out2 + (long long)b * ((long long)S_ * H_);
            const int h0 = (colBase - 2048) + hh * 64;
#pragma unroll 8
            for (int h = 0; h < 64; ++h)
                vt[(long long)(h0 + h) * S_ + s_glob] = T[s_loc][hh * 64 + h];
        }
    } else if constexpr (EPI == 4) {
        // PV: normalize rows by 1/l (l passed via bias pointer)
        unsigned short* dst = (unsigned short*)out0 + (long long)tz * sOz;
#pragma unroll
        for (int m = 0; m < 4; m++) {
            float linv[4];
#pragma unroll
            for (int j = 0; j < 4; j++)
                linv[j] = 1.0f / bias[tz * 2048 + crow0 + m * 16 + j];
#pragma unroll
            for (int n = 0; n < 4; n++) {
                const int col = ccol0 + n * 16;
                const int r0 = crow0 + m * 16;
#pragma unroll
                for (int j = 0; j < 4; j++)
                    dst[(long long)(r0 + j) * N + col] = f2bf(acc[m][n][j] * linv[j]);
            }
        }
        (void)scale;
    } else {
        // EPI 3: f32 out + bias
        float* dst = (float*)out0;
#pragma unroll
        for (int n = 0; n < 4; n++) {
            const int col = ccol0 + n * 16;
            const float bv = bias[col];
#pragma unroll
            for (int m = 0; m < 4; m++) {
                const int r0 = crow0 + m * 16;
#pragma unroll
                for (int j = 0; j < 4; j++)
                    dst[(long long)(r0 + j) * N + col] = acc[m][n][j] + bv;
            }
        }
        (void)scale;
    }
}

// ---------------------------------------------------------------------------
// gemm256: 256x256 8-phase kernel (core verified rounds 2-6), now with
// 1D XCD-chunked grid (batch-aligned L2 chunks) and EPI=2 epilogue:
// P~ = exp(acc*scale) written bf16; per-row l accumulated via shfl-reduce
// over the 16 fr-lanes + one atomicAdd per row-frag (out1 = l array, f32).
// ---------------------------------------------------------------------------
template<int EPI>
__global__ __launch_bounds__(512, 2) void gemm256(
    const unsigned short* __restrict__ A,
    const unsigned short* __restrict__ Bm,
    int NXt, int NYt, int N, int K,
    long long sAz, long long sBz, long long sOz,
    void* __restrict__ out0, void* __restrict__ out1, void* __restrict__ out2,
    const float* __restrict__ bias, float scale)
{
    __shared__ __align__(16) char lds[131072];

    // XCD chunking + 2D sub-order (requires (grid/8) % (4*NXt) == 0)
    const int nt_g = (int)gridDim.x;
    const int bid = (int)blockIdx.x;
    const int C = nt_g >> 3;
    const int c = bid >> 3;
    const int xcd = bid & 7;
    const int qq = c >> 2;
    const int txl = qq % NXt;
    const int rest = (c & 3) + 4 * (qq / NXt);
    const int tile = xcd * C + rest * NXt + txl;
    const int tx = tile % NXt;
    const int rest2 = tile / NXt;
    const int ty = rest2 % NYt;
    const int tz = rest2 / NYt;

    const unsigned short* Ab = A  + (long long)tz * sAz;
    const unsigned short* Bb = Bm + (long long)tz * sBz;
    const int rowBase = ty * 256;
    const int colBase = tx * 256;
    const int tid = threadIdx.x;
    const int w = tid >> 6, l = tid & 63;
    const int wr = w >> 2, wc = w & 3;
    const int fr = l & 15, fq = l >> 4;

    int sr[2], scl[2];
#pragma unroll
    for (int j = 0; j < 2; j++) {
        int o  = j * 8192 + tid * 16;
        int st = o >> 10;
        int wi = o & 1023;
        wi ^= ((wi >> 9) & 1) << 5;
        sr[j]  = (st >> 1) * 16 + (wi >> 6);
        scl[j] = (st & 1) * 32 + ((wi & 63) >> 1);
    }

    auto STAGE = [&](int buf, int which, int tile_) {
        const unsigned short* mat = (which < 2) ? Ab : Bb;
        const int rt0 = ((which < 2) ? rowBase : colBase) + (which & 1) * 128;
        char* dst = lds + buf * 65536 + (which >> 1) * 32768
                        + (which & 1) * 16384 + w * 1024;
        const int k0 = tile_ * 64;
#pragma unroll
        for (int j = 0; j < 2; j++) {
            const unsigned short* src =
                mat + (long long)(rt0 + sr[j]) * K + k0 + scl[j];
            gload_lds16(src, dst + j * 8192);
        }
    };

    const int abase = (fr * 64 + fq * 16) ^ ((fr & 8) << 2);
    const char* Ah[2] = { lds + wr * 16384, lds + 65536 + wr * 16384 };
    const char* Bh[2] = { lds + 32768 + (wc >> 1) * 16384,
                          lds + 98304 + (wc >> 1) * 16384 };
    const int bn0 = (wc & 1) * 8192;

#define LA(b, m, kk) (*(const bf16x8*)(Ah[b] + (m)*2048 + (kk)*1024 + abase))
#define LB(b, n, kk) (*(const bf16x8*)(Bh[b] + bn0 + (n)*2048 + (kk)*1024 + abase))
#define MFMA16(AF, BF, MOFF, NOFF) do { \
    __builtin_amdgcn_s_setprio(1); \
    _Pragma("unroll") for (int m_ = 0; m_ < 4; m_++) \
    _Pragma("unroll") for (int n_ = 0; n_ < 2; n_++) \
    _Pragma("unroll") for (int k_ = 0; k_ < 2; k_++) \
        acc[(MOFF)+m_][(NOFF)+n_] = __builtin_amdgcn_mfma_f32_16x16x32_bf16( \
            AF[m_][k_], BF[n_][k_], acc[(MOFF)+m_][(NOFF)+n_], 0, 0, 0); \
    __builtin_amdgcn_s_setprio(0); } while (0)

    f32x4 acc[8][4];
#pragma unroll
    for (int m = 0; m < 8; m++)
#pragma unroll
        for (int n = 0; n < 4; n++) acc[m][n] = (f32x4){0.f, 0.f, 0.f, 0.f};

    const int NT = K >> 6;

    STAGE(0, 0, 0); STAGE(0, 1, 0); STAGE(0, 2, 0); STAGE(0, 3, 0);
    STAGE(1, 0, 1); STAGE(1, 1, 1);
    asm volatile("s_waitcnt vmcnt(4)" ::: "memory");
    BAR;
    __builtin_amdgcn_sched_barrier(0);

    bf16x8 afA[4][2], afB[4][2], bfA[2][2], bfB[2][2];

    for (int i = 0; i < NT / 2; i++) {
        const int t1 = 2 * i + 1;
        int t2 = 2 * i + 2; if (t2 >= NT) t2 -= NT;
        int t3 = 2 * i + 3; if (t3 >= NT) t3 -= NT;

#pragma unroll
        for (int m = 0; m < 4; m++) { afA[m][0] = LA(0, m, 0); afA[m][1] = LA(0, m, 1); }
#pragma unroll
        for (int n = 0; n < 2; n++) { bfA[n][0] = LB(0, n, 0); bfA[n][1] = LB(0, n, 1); }
        STAGE(1, 2, t1);
        BAR; DS_FENCE;
        MFMA16(afA, bfA, 0, 0);
        BAR;
#pragma unroll
        for (int m = 0; m < 4; m++) { afB[m][0] = LA(0, 4 + m, 0); afB[m][1] = LA(0, 4 + m, 1); }
        STAGE(1, 3, t1);
        BAR; DS_FENCE;
        MFMA16(afB, bfA, 4, 0);
        BAR;
#pragma unroll
        for (int n = 0; n < 2; n++) { bfB[n][0] = LB(0, 2 + n, 0); bfB[n][1] = LB(0, 2 + n, 1); }
        STAGE(0, 0, t2);
        BAR; DS_FENCE;
        MFMA16(afA, bfB, 0, 2);
        BAR;
        STAGE(0, 1, t2);
        BAR;
        MFMA16(afB, bfB, 4, 2);
        asm volatile("s_waitcnt vmcnt(4)" ::: "memory");
        BAR;
        __builtin_amdgcn_sched_barrier(0);

#pragma unroll
        for (int m = 0; m < 4; m++) { afA[m][0] = LA(1, m, 0); afA[m][1] = LA(1, m, 1); }
#pragma unroll
        for (int n = 0; n < 2; n++) { bfA[n][0] = LB(1, n, 0); bfA[n][1] = LB(1, n, 1); }
        STAGE(0, 2, t2);
        BAR; DS_FENCE;
        MFMA16(afA, bfA, 0, 0);
        BAR;
#pragma unroll
        for (int m = 0; m < 4; m++) { afB[m][0] = LA(1, 4 + m, 0); afB[m][1] = LA(1, 4 + m, 1); }
        STAGE(0, 3, t2);
        BAR; DS_FENCE;
        MFMA16(afB, bfA, 4, 0);
        BAR;
#pragma unroll
        for (int n = 0; n < 2; n++) { bfB[n][0] = LB(1, 2 + n, 0); bfB[n][1] = LB(1, 2 + n, 1); }
        STAGE(1, 0, t3);
        BAR; DS_FENCE;
        MFMA16(afA, bfB, 0, 2);
        BAR;
        STAGE(1, 1, t3);
        BAR;
        MFMA16(afB, bfB, 4, 2);
        asm volatile("s_waitcnt vmcnt(4)" ::: "memory");
        BAR;
        __builtin_amdgcn_sched_barrier(0);
    }

    asm volatile("s_waitcnt vmcnt(0) lgkmcnt(0)" ::: "memory");

    const int crow0 = rowBase + wr * 128 + fq * 4;
    const int ccol0 = colBase + wc * 64 + fr;

    if constexpr (EPI == 2) {
        float* lsum = (float*)out1;
        unsigned short* dst = (unsigned short*)out0 + (long long)tz * sOz;
#pragma unroll
        for (int m = 0; m < 8; m++) {
#pragma unroll
            for (int j = 0; j < 4; j++) {
                const int row = crow0 + m * 16 + j;
                float rs = 0.f;
#pragma unroll
                for (int n = 0; n < 4; n++) {
                    const int col = ccol0 + n * 16;
                    const float p = __expf(acc[m][n][j] * scale);
                    const unsigned short us = f2bf(p);
                    dst[(long long)row * N + col] = us;
                    rs += bf2f(us);
                }
                rs += __shfl_xor(rs, 1); rs += __shfl_xor(rs, 2);
                rs += __shfl_xor(rs, 4); rs += __shfl_xor(rs, 8);
                if (fr == 0) atomicAdd(&lsum[tz * 2048 + row], rs);
            }
        }
    }
    (void)out2; (void)bias;
#undef LA
#undef LB
#undef MFMA16
}

// f32 -> bf16 elementwise (8/thread, vectorized)
__global__ __launch_bounds__(256) void conv_f32_bf16(
    const float* __restrict__ in, unsigned short* __restrict__ out, int n8)
{
    for (int i = blockIdx.x * blockDim.x + threadIdx.x; i < n8;
         i += gridDim.x * blockDim.x) {
        const float4 a = ((const float4*)in)[2 * i];
        const float4 b = ((const float4*)in)[2 * i + 1];
        u16x8 o;
        o[0] = f2bf(a.x); o[1] = f2bf(a.y); o[2] = f2bf(a.z); o[3] = f2bf(a.w);
        o[4] = f2bf(b.x); o[5] = f2bf(b.y); o[6] = f2bf(b.z); o[7] = f2bf(b.w);
        ((u16x8*)out)[i] = o;
    }
}

// out[cols][rows] (bf16) = transpose(in[rows][cols] f32)
__global__ __launch_bounds__(256) void tconv_f32_bf16(
    const float* __restrict__ in, unsigned short* __restrict__ out,
    int rows, int cols)
{
    __shared__ float t[32][33];
    const int c0 = blockIdx.x * 32, r0 = blockIdx.y * 32;
    const int tx = threadIdx.x & 31, ty = threadIdx.x >> 5;
#pragma unroll
    for (int i = 0; i < 4; i++)
        t[ty + 8 * i][tx] = in[(long long)(r0 + ty + 8 * i) * cols + c0 + tx];
    __syncthreads();
#pragma unroll
    for (int i = 0; i < 4; i++)
        out[(long long)(c0 + ty + 8 * i) * rows + r0 + tx] = f2bf(t[tx][ty + 8 * i]);
}

extern "C" void kernel_launch(void* const* d_in, const int* in_sizes, int n_in,
                              void* d_out, int out_size, void* d_ws, size_t ws_size,
                              hipStream_t stream)
{
    (void)in_sizes; (void)n_in; (void)out_size; (void)ws_size;
    const float* x  = (const float*)d_in[0];
    const float* W1 = (const float*)d_in[1];
    const float* b1 = (const float*)d_in[2];
    const float* W2 = (const float*)d_in[3];
    const float* b2 = (const float*)d_in[4];
    float* out = (float*)d_out;

    char* ws = (char*)d_ws;
    size_t off = 0;
    auto alloc = [&](size_t bytes) {
        void* p = ws + off;
        off += (bytes + 255) & ~(size_t)255;
        return p;
    };
    unsigned short* xbf = (unsigned short*)alloc((size_t)BS_ * D_ * 2);
    unsigned short* w1t = (unsigned short*)alloc((size_t)N3H * D_ * 2);
    unsigned short* w2t = (unsigned short*)alloc((size_t)H_ * H_ * 2);
    unsigned short* q   = (unsigned short*)alloc((size_t)BS_ * H_ * 2);
    unsigned short* k   = (unsigned short*)alloc((size_t)BS_ * H_ * 2);
    unsigned short* v   = (unsigned short*)alloc((size_t)BS_ * H_ * 2);  // ctx
    unsigned short* vt  = (unsigned short*)alloc((size_t)BS_ * H_ * 2);
    unsigned short* sc  = (unsigned short*)alloc((size_t)B_ * S_ * S_ * 2);
    float*          lsum = (float*)alloc((size_t)BS_ * 4);
    unsigned short* ctx = v;  // v is never materialized; reuse its slot

    const float scale = 0.022097086912079608f;  // (2*D)^-0.5 = 1/sqrt(2048)

    hipMemsetAsync(lsum, 0, (size_t)BS_ * 4, stream);

    conv_f32_bf16<<<dim3(2048), dim3(256), 0, stream>>>(x, xbf, BS_ * D_ / 8);
    tconv_f32_bf16<<<dim3(N3H / 32, D_ / 32), dim3(256), 0, stream>>>(W1, w1t, D_, N3H);
    tconv_f32_bf16<<<dim3(H_ / 32, H_ / 32), dim3(256), 0, stream>>>(W2, w2t, H_, H_);

    // QKV: [8192,3072] = xbf @ w1t^T, split q/k (+bias) and vt (transposed).
    gemm3b<0><<<dim3(1536), dim3(256), 0, stream>>>(
        xbf, w1t, 24, 64, N3H, D_, 0LL, 0LL, 0LL, q, k, vt, b1, 1.0f);

    // P~[b] = exp((q[b] @ k[b]^T) * scale) bf16 + per-row l atomics.
    gemm256<2><<<dim3(256), dim3(512), 0, stream>>>(
        q, k, 8, 8, S_, H_, (long long)S_ * H_, (long long)S_ * H_,
        (long long)S_ * S_, sc, lsum, nullptr, nullptr, scale);

    // ctx[b] = (P~[b] @ vt[b]^T) / l  [2048,1024] bf16
    gemm3b<4><<<dim3(512), dim3(256), 0, stream>>>(
        sc, vt, 8, 16, H_, S_, (long long)S_ * S_, (long long)H_ * S_,
        (long long)S_ * H_, ctx, nullptr, nullptr, lsum, 1.0f);

    // out = ctx @ w2t^T + b2  [8192,1024] f32
    gemm3b<3><<<dim3(512), dim3(256), 0, stream>>>(
        ctx, w2t, 8, 64, H_, H_, 0LL, 0LL, 0LL, out, nullptr, nullptr, b2, 1.0f);
}